// Round 1
// baseline (718.204 us; speedup 1.0000x reference)
//
#include <hip/hip_runtime.h>
#include <hip/hip_bf16.h>

#define NROW 1024
#define DDIM 512
#define CDIM 85742
#define SSC 64.0f
#define MARG 0.5f
#define AEPS 1e-7f

typedef __attribute__((ext_vector_type(8))) short bf16x8;
typedef __attribute__((ext_vector_type(4))) float f32x4;

__device__ __forceinline__ void async_ld16(const void* g, void* l) {
  __builtin_amdgcn_global_load_lds((const __attribute__((address_space(1))) void*)g,
                                   (__attribute__((address_space(3))) void*)l, 16, 0, 0);
}

// One wave per row: L2-normalize x row, emit bf16.
__global__ void row_normalize(const float* __restrict__ x, __hip_bfloat16* __restrict__ xn) {
  const int row = blockIdx.x;
  const int lane = threadIdx.x;  // 64 threads
  const float4* xr = (const float4*)(x + (size_t)row * DDIM);
  float4 a = xr[lane * 2 + 0];
  float4 b = xr[lane * 2 + 1];
  float ss = a.x * a.x + a.y * a.y + a.z * a.z + a.w * a.w +
             b.x * b.x + b.y * b.y + b.z * b.z + b.w * b.w;
#pragma unroll
  for (int o = 32; o >= 1; o >>= 1) ss += __shfl_xor(ss, o);
  const float inv = 1.0f / fmaxf(sqrtf(ss), 1e-12f);
  __hip_bfloat16 t[8];
  t[0] = __float2bfloat16(a.x * inv); t[1] = __float2bfloat16(a.y * inv);
  t[2] = __float2bfloat16(a.z * inv); t[3] = __float2bfloat16(a.w * inv);
  t[4] = __float2bfloat16(b.x * inv); t[5] = __float2bfloat16(b.y * inv);
  t[6] = __float2bfloat16(b.z * inv); t[7] = __float2bfloat16(b.w * inv);
  *(bf16x8*)(xn + (size_t)row * DDIM + lane * 8) = *(bf16x8*)t;
}

// fp32 W -> bf16 (one-time per launch; grid-stride, 8 floats/thread/iter)
__global__ void convert_w(const float* __restrict__ W, __hip_bfloat16* __restrict__ Wb) {
  const int n8 = CDIM * DDIM / 8;
  int i = blockIdx.x * blockDim.x + threadIdx.x;
  const int stride = gridDim.x * blockDim.x;
  for (; i < n8; i += stride) {
    float4 a = ((const float4*)W)[(size_t)i * 2 + 0];
    float4 b = ((const float4*)W)[(size_t)i * 2 + 1];
    __hip_bfloat16 t[8];
    t[0] = __float2bfloat16(a.x); t[1] = __float2bfloat16(a.y);
    t[2] = __float2bfloat16(a.z); t[3] = __float2bfloat16(a.w);
    t[4] = __float2bfloat16(b.x); t[5] = __float2bfloat16(b.y);
    t[6] = __float2bfloat16(b.z); t[7] = __float2bfloat16(b.w);
    ((bf16x8*)Wb)[i] = *(bf16x8*)t;
  }
}

// 128x128 tile, BK=32, 4 waves (2x2), 16x16x32 bf16 MFMA.
// A = xn [1024][512] bf16 (K-contiguous), B = W [C][512] (K-contiguous) -> wf = A * B^T.
// Epilogue: store wf fp32, atomicAdd per-row sum of exp(S*wf) into rowsum.
template <bool WB16>
__global__ __launch_bounds__(256) void gemm_loss(const __hip_bfloat16* __restrict__ A,
                                                 const void* __restrict__ Wsrc,
                                                 float* __restrict__ wf,
                                                 float* __restrict__ rowsum) {
  __shared__ __hip_bfloat16 As[128 * 32];
  __shared__ __hip_bfloat16 Bs[128 * 32];
  const int tid = threadIdx.x;
  const int lane = tid & 63;
  const int wav = tid >> 6;
  const int wm = wav >> 1, wn = wav & 1;
  const int row0 = blockIdx.x * 128;  // M tile (8 tiles)
  const int col0 = blockIdx.y * 128;  // C tile (670 tiles)
  const int lr = lane & 15, lq = lane >> 4;
  const int ldsWaveBase = (tid & ~63) * 8;  // elements; lane adds 16B automatically

  f32x4 acc[4][4] = {};

  for (int k0 = 0; k0 < DDIM; k0 += 32) {
    // ---- stage A tile (128x32 bf16 = 8KB) via global_load_lds width 16
#pragma unroll
    for (int q = 0; q < 2; ++q) {
      const int chunk = q * 256 + tid;
      const int r = chunk >> 2, kc = chunk & 3;
      async_ld16(A + ((size_t)(row0 + r) * DDIM + k0 + kc * 8),
                 As + (q * 256 * 8 + ldsWaveBase));
    }
    // ---- stage B tile
    if (WB16) {
      const __hip_bfloat16* Wb = (const __hip_bfloat16*)Wsrc;
#pragma unroll
      for (int q = 0; q < 2; ++q) {
        const int chunk = q * 256 + tid;
        const int r = chunk >> 2, kc = chunk & 3;
        int gr = col0 + r;
        gr = gr < CDIM ? gr : CDIM - 1;  // clamp address; masked in epilogue
        async_ld16(Wb + ((size_t)gr * DDIM + k0 + kc * 8),
                   Bs + (q * 256 * 8 + ldsWaveBase));
      }
    } else {
      const float* Wf = (const float*)Wsrc;
#pragma unroll
      for (int q = 0; q < 2; ++q) {
        const int chunk = q * 256 + tid;
        const int r = chunk >> 2, kc = chunk & 3;
        int gr = col0 + r;
        gr = gr < CDIM ? gr : CDIM - 1;
        const float4* g = (const float4*)(Wf + (size_t)gr * DDIM + k0 + kc * 8);
        float4 va = g[0], vb = g[1];
        __hip_bfloat16 t[8];
        t[0] = __float2bfloat16(va.x); t[1] = __float2bfloat16(va.y);
        t[2] = __float2bfloat16(va.z); t[3] = __float2bfloat16(va.w);
        t[4] = __float2bfloat16(vb.x); t[5] = __float2bfloat16(vb.y);
        t[6] = __float2bfloat16(vb.z); t[7] = __float2bfloat16(vb.w);
        *(bf16x8*)(Bs + chunk * 8) = *(bf16x8*)t;
      }
    }
    __syncthreads();

    // ---- fragments + MFMA
    bf16x8 af[4], bfr[4];
#pragma unroll
    for (int i = 0; i < 4; ++i) {
      af[i]  = *(const bf16x8*)(As + (wm * 64 + i * 16 + lr) * 32 + lq * 8);
      bfr[i] = *(const bf16x8*)(Bs + (wn * 64 + i * 16 + lr) * 32 + lq * 8);
    }
#pragma unroll
    for (int i = 0; i < 4; ++i)
#pragma unroll
      for (int j = 0; j < 4; ++j)
        acc[i][j] = __builtin_amdgcn_mfma_f32_16x16x32_bf16(af[i], bfr[j], acc[i][j], 0, 0, 0);
    __syncthreads();
  }

  // ---- epilogue: store wf, per-row exp-sum partials
#pragma unroll
  for (int i = 0; i < 4; ++i) {
    const int rb = row0 + wm * 64 + i * 16 + lq * 4;
#pragma unroll
    for (int r = 0; r < 4; ++r) {
      const int grow = rb + r;
      float esum = 0.f;
#pragma unroll
      for (int j = 0; j < 4; ++j) {
        const int gcol = col0 + wn * 64 + j * 16 + lr;
        const float v = acc[i][j][r];
        if (gcol < CDIM) {
          wf[(size_t)grow * CDIM + gcol] = v;
          esum += __expf(SSC * v);
        }
      }
      // reduce across the 16 lanes of the quad (cols)
      esum += __shfl_xor(esum, 1);
      esum += __shfl_xor(esum, 2);
      esum += __shfl_xor(esum, 4);
      esum += __shfl_xor(esum, 8);
      if (lr == 0) atomicAdd(rowsum + grow, esum);
    }
  }
}

// One block, 1024 threads: arcface loss from wf + rowsum.
__global__ void finalize(const float* __restrict__ wf, const float* __restrict__ rowsum,
                         const int* __restrict__ labels, float* __restrict__ out_loss) {
  const int i = threadIdx.x;
  const int lab = labels[i];
  const float tgt = wf[(size_t)i * CDIM + lab];
  const float tc = fminf(fmaxf(tgt, -1.0f + AEPS), 1.0f - AEPS);
  const float num = SSC * cosf(acosf(tc) + MARG);
  const float excl = rowsum[i] - __expf(SSC * tgt);
  float L = num - logf(__expf(num) + excl);
#pragma unroll
  for (int o = 32; o >= 1; o >>= 1) L += __shfl_xor(L, o);
  __shared__ float red[16];
  if ((i & 63) == 0) red[i >> 6] = L;
  __syncthreads();
  if (i < 64) {
    float v = (i < 16) ? red[i] : 0.f;
#pragma unroll
    for (int o = 8; o >= 1; o >>= 1) v += __shfl_xor(v, o);
    if (i == 0) out_loss[0] = -v * (1.0f / NROW);
  }
}

extern "C" void kernel_launch(void* const* d_in, const int* in_sizes, int n_in,
                              void* d_out, int out_size, void* d_ws, size_t ws_size,
                              hipStream_t stream) {
  const float* x = (const float*)d_in[0];
  const float* W = (const float*)d_in[1];
  const int* labels = (const int*)d_in[2];
  float* out = (float*)d_out;

  // workspace layout: [0,4K) rowsum fp32[1024]; [4K, 4K+1M) xn bf16; then W bf16
  float* rowsum = (float*)d_ws;
  __hip_bfloat16* xn = (__hip_bfloat16*)((char*)d_ws + 4096);
  __hip_bfloat16* Wb = (__hip_bfloat16*)((char*)d_ws + 4096 + (size_t)NROW * DDIM * 2);
  const size_t need = 4096 + (size_t)NROW * DDIM * 2 + (size_t)CDIM * DDIM * 2;
  const bool wb16 = ws_size >= need;

  hipMemsetAsync(d_ws, 0, 4096, stream);  // zero rowsum (ws is poisoned 0xAA)
  row_normalize<<<NROW, 64, 0, stream>>>(x, xn);

  dim3 grid(8, (CDIM + 127) / 128);  // 8 x 670
  if (wb16) {
    convert_w<<<2048, 256, 0, stream>>>(W, Wb);
    gemm_loss<true><<<grid, 256, 0, stream>>>(xn, (const void*)Wb, out, rowsum);
  } else {
    gemm_loss<false><<<grid, 256, 0, stream>>>(xn, (const void*)W, out, rowsum);
  }
  finalize<<<1, 1024, 0, stream>>>(out, rowsum, labels, out + (size_t)NROW * CDIM);
}

// Round 2
// 653.946 us; speedup vs baseline: 1.0983x; 1.0983x over previous
//
#include <hip/hip_runtime.h>
#include <hip/hip_bf16.h>

#define NROW 1024
#define DDIM 512
#define CDIM 85742
#define SSC 64.0f
#define MARG 0.5f
#define AEPS 1e-7f

typedef __attribute__((ext_vector_type(8))) short bf16x8;
typedef __attribute__((ext_vector_type(4))) float f32x4;

__device__ __forceinline__ void async_ld16(const void* g, void* l) {
  __builtin_amdgcn_global_load_lds((const __attribute__((address_space(1))) void*)g,
                                   (__attribute__((address_space(3))) void*)l, 16, 0, 0);
}

// One wave per row: L2-normalize x row, emit bf16. Also zeroes rowsum[row].
__global__ void row_normalize(const float* __restrict__ x, __hip_bfloat16* __restrict__ xn,
                              float* __restrict__ rowsum) {
  const int row = blockIdx.x;
  const int lane = threadIdx.x;  // 64 threads
  if (lane == 0) rowsum[row] = 0.0f;
  const float4* xr = (const float4*)(x + (size_t)row * DDIM);
  float4 a = xr[lane * 2 + 0];
  float4 b = xr[lane * 2 + 1];
  float ss = a.x * a.x + a.y * a.y + a.z * a.z + a.w * a.w +
             b.x * b.x + b.y * b.y + b.z * b.z + b.w * b.w;
#pragma unroll
  for (int o = 32; o >= 1; o >>= 1) ss += __shfl_xor(ss, o);
  const float inv = 1.0f / fmaxf(sqrtf(ss), 1e-12f);
  __hip_bfloat16 t[8];
  t[0] = __float2bfloat16(a.x * inv); t[1] = __float2bfloat16(a.y * inv);
  t[2] = __float2bfloat16(a.z * inv); t[3] = __float2bfloat16(a.w * inv);
  t[4] = __float2bfloat16(b.x * inv); t[5] = __float2bfloat16(b.y * inv);
  t[6] = __float2bfloat16(b.z * inv); t[7] = __float2bfloat16(b.w * inv);
  *(bf16x8*)(xn + (size_t)row * DDIM + lane * 8) = *(bf16x8*)t;
}

__device__ __forceinline__ bf16x8 cvt8(f32x4 lo, f32x4 hi) {
  __hip_bfloat16 t[8];
  t[0] = __float2bfloat16(lo.x); t[1] = __float2bfloat16(lo.y);
  t[2] = __float2bfloat16(lo.z); t[3] = __float2bfloat16(lo.w);
  t[4] = __float2bfloat16(hi.x); t[5] = __float2bfloat16(hi.y);
  t[6] = __float2bfloat16(hi.z); t[7] = __float2bfloat16(hi.w);
  return *(bf16x8*)t;
}

// 128x128 tile, BK=32, 4 waves (2x2), 16x16x32 bf16 MFMA.
// A = xn bf16 (async staged). B = W fp32 staged raw into LDS (XOR-swizzled
// 16B chunks to kill 16-way bank conflicts), converted to bf16 at frag read.
// Grid: 1-D 5376.  x=id&7 selects an XCD-stripe of 84 column-tiles; the 8
// M-tiles of one column dispatch within 64 ids on the same XCD -> W slab L2-hit.
__global__ __launch_bounds__(256) void gemm_loss(const __hip_bfloat16* __restrict__ A,
                                                 const float* __restrict__ W,
                                                 float* __restrict__ wf,
                                                 float* __restrict__ rowsum) {
  const int id = blockIdx.x;
  const int xcd = id & 7;
  const int s = id >> 3;
  const int ctile = xcd * 84 + (s >> 3);
  if (ctile >= 670) return;  // 16 pad blocks
  const int mtile = s & 7;

  __shared__ __hip_bfloat16 As[128 * 32];  // 8 KB
  __shared__ float Bs[128 * 32];           // 16 KB, swizzled 16B chunks
  const int tid = threadIdx.x;
  const int lane = tid & 63;
  const int wav = tid >> 6;
  const int wm = wav >> 1, wn = wav & 1;
  const int row0 = mtile * 128;
  const int col0 = ctile * 128;
  const int lr = lane & 15, lq = lane >> 4;
  const int waveBase = tid & ~63;

  f32x4 acc[4][4] = {};

  for (int k0 = 0; k0 < DDIM; k0 += 32) {
    // ---- stage A tile (128x32 bf16 = 8KB): 512 chunks of 16B
#pragma unroll
    for (int q = 0; q < 2; ++q) {
      const int chunk = q * 256 + tid;
      const int r = chunk >> 2, kc = chunk & 3;
      async_ld16(A + ((size_t)(row0 + r) * DDIM + k0 + kc * 8),
                 As + (q * 256 + waveBase) * 8);
    }
    // ---- stage B tile fp32 (128x32 = 16KB): 1024 chunks of 16B, XOR swizzle
#pragma unroll
    for (int q = 0; q < 4; ++q) {
      const int chunk = q * 256 + tid;
      const int r = chunk >> 3, kc = chunk & 7;
      const int kcs = kc ^ (r & 7);  // slot kc holds global chunk kc^(r&7)
      int gr = col0 + r;
      gr = gr < CDIM ? gr : CDIM - 1;  // clamp address; masked in epilogue
      async_ld16(W + ((size_t)gr * DDIM + k0 + kcs * 4),
                 Bs + (q * 256 + waveBase) * 4);
    }
    __syncthreads();

    // ---- fragments + MFMA
    bf16x8 af[4], bfr[4];
#pragma unroll
    for (int i = 0; i < 4; ++i)
      af[i] = *(const bf16x8*)(As + (wm * 64 + i * 16 + lr) * 32 + lq * 8);
#pragma unroll
    for (int j = 0; j < 4; ++j) {
      const int br = wn * 64 + j * 16 + lr;
      const int s0 = (2 * lq) ^ (br & 7);
      const int s1 = (2 * lq + 1) ^ (br & 7);
      f32x4 lo = *(const f32x4*)(Bs + br * 32 + s0 * 4);
      f32x4 hi = *(const f32x4*)(Bs + br * 32 + s1 * 4);
      bfr[j] = cvt8(lo, hi);
    }
#pragma unroll
    for (int i = 0; i < 4; ++i)
#pragma unroll
      for (int j = 0; j < 4; ++j)
        acc[i][j] = __builtin_amdgcn_mfma_f32_16x16x32_bf16(af[i], bfr[j], acc[i][j], 0, 0, 0);
    __syncthreads();
  }

  // ---- epilogue: store wf, per-row exp-sum partials
#pragma unroll
  for (int i = 0; i < 4; ++i) {
    const int rb = row0 + wm * 64 + i * 16 + lq * 4;
#pragma unroll
    for (int r = 0; r < 4; ++r) {
      const int grow = rb + r;
      float esum = 0.f;
#pragma unroll
      for (int j = 0; j < 4; ++j) {
        const int gcol = col0 + wn * 64 + j * 16 + lr;
        const float v = acc[i][j][r];
        if (gcol < CDIM) {
          wf[(size_t)grow * CDIM + gcol] = v;
          esum += __expf(SSC * v);
        }
      }
      esum += __shfl_xor(esum, 1);
      esum += __shfl_xor(esum, 2);
      esum += __shfl_xor(esum, 4);
      esum += __shfl_xor(esum, 8);
      if (lr == 0) atomicAdd(rowsum + grow, esum);
    }
  }
}

// One block, 1024 threads: arcface loss from wf + rowsum.
__global__ void finalize(const float* __restrict__ wf, const float* __restrict__ rowsum,
                         const int* __restrict__ labels, float* __restrict__ out_loss) {
  const int i = threadIdx.x;
  const int lab = labels[i];
  const float tgt = wf[(size_t)i * CDIM + lab];
  const float tc = fminf(fmaxf(tgt, -1.0f + AEPS), 1.0f - AEPS);
  const float num = SSC * cosf(acosf(tc) + MARG);
  const float excl = rowsum[i] - __expf(SSC * tgt);
  float L = num - logf(__expf(num) + excl);
#pragma unroll
  for (int o = 32; o >= 1; o >>= 1) L += __shfl_xor(L, o);
  __shared__ float red[16];
  if ((i & 63) == 0) red[i >> 6] = L;
  __syncthreads();
  if (i < 64) {
    float v = (i < 16) ? red[i] : 0.f;
#pragma unroll
    for (int o = 8; o >= 1; o >>= 1) v += __shfl_xor(v, o);
    if (i == 0) out_loss[0] = -v * (1.0f / NROW);
  }
}

extern "C" void kernel_launch(void* const* d_in, const int* in_sizes, int n_in,
                              void* d_out, int out_size, void* d_ws, size_t ws_size,
                              hipStream_t stream) {
  const float* x = (const float*)d_in[0];
  const float* W = (const float*)d_in[1];
  const int* labels = (const int*)d_in[2];
  float* out = (float*)d_out;

  // workspace: [0,4K) rowsum fp32[1024]; [4K,...) xn bf16[1024*512]
  float* rowsum = (float*)d_ws;
  __hip_bfloat16* xn = (__hip_bfloat16*)((char*)d_ws + 4096);

  row_normalize<<<NROW, 64, 0, stream>>>(x, xn, rowsum);
  gemm_loss<<<672 * 8, 256, 0, stream>>>(xn, W, out, rowsum);
  finalize<<<1, 1024, 0, stream>>>(out, rowsum, labels, out + (size_t)NROW * CDIM);
}